// Round 9
// baseline (780.895 us; speedup 1.0000x reference)
//
#include <hip/hip_runtime.h>

// ---------------------------------------------------------------------------
// GCN 4-layer inference.
//  - GEMMs: NO LDS, NO barriers. W (tiny, L2/L1-resident) is read per-lane
//    directly into MFMA B-fragments via dwordx4; waves run free, latency
//    hidden by dataflow + MFMA overlap. 8 waves x 32 rows (BM=256).
//    Layer-1: split-bf16 (3 mfma = ~fp32). Layers 2/3: fp16 W-hi/lo (2 mfma).
//  - Activations between layers fp16 (exact under re-read).
//  - Aggregation: CSR gather of fp16 rows, 4-deep software-pipelined.
// ---------------------------------------------------------------------------

#define DEV __device__ __forceinline__

typedef __attribute__((ext_vector_type(8))) short short8;
typedef __attribute__((ext_vector_type(8))) _Float16 f16x8;
typedef __attribute__((ext_vector_type(4))) float f32x4;
typedef __attribute__((ext_vector_type(4))) _Float16 f16x4;

DEV unsigned short f2bf(float x) {                 // fp32 -> bf16 RNE
    unsigned u = __builtin_bit_cast(unsigned, x);
    u += 0x7FFFu + ((u >> 16) & 1u);
    return (unsigned short)(u >> 16);
}
DEV float bf2f(unsigned short b) {
    return __builtin_bit_cast(float, (unsigned)b << 16);
}

// ---------------- CSR build ----------------

__global__ void k_init(int* __restrict__ cnt, int* __restrict__ fill, int n) {
    int i = blockIdx.x * 256 + threadIdx.x;
    if (i < n) { cnt[i] = 1; fill[i] = 0; }   // 1 = self-loop
}

__global__ void k_count(const int* __restrict__ dst, int* __restrict__ cnt, int E) {
    int e = blockIdx.x * 256 + threadIdx.x;
    if (e < E) atomicAdd(&cnt[dst[e]], 1);
}

__global__ void k_scan1(const int* __restrict__ cnt, int* __restrict__ row_start,
                        int* __restrict__ partial, float* __restrict__ dinv, int n) {
    __shared__ int sdata[256];
    int base = blockIdx.x * 1024;
    int t = threadIdx.x;
    int v[4]; int sum = 0;
#pragma unroll
    for (int j = 0; j < 4; ++j) {
        int idx = base + t * 4 + j;
        v[j] = (idx < n) ? cnt[idx] : 0;
        if (idx < n) dinv[idx] = rsqrtf((float)v[j]);
        sum += v[j];
    }
    sdata[t] = sum;
    __syncthreads();
    for (int off = 1; off < 256; off <<= 1) {
        int x = (t >= off) ? sdata[t - off] : 0;
        __syncthreads();
        sdata[t] += x;
        __syncthreads();
    }
    int excl = sdata[t] - sum;
#pragma unroll
    for (int j = 0; j < 4; ++j) {
        int idx = base + t * 4 + j;
        if (idx < n) row_start[idx] = excl;
        excl += v[j];
    }
    if (t == 255) partial[blockIdx.x] = sdata[255];
}

__global__ void k_scan2(int* __restrict__ partial, int nb) {
    __shared__ int s[128];
    int t = threadIdx.x;
    int v = (t < nb) ? partial[t] : 0;
    s[t] = v;
    __syncthreads();
    for (int off = 1; off < 128; off <<= 1) {
        int x = (t >= off) ? s[t - off] : 0;
        __syncthreads();
        s[t] += x;
        __syncthreads();
    }
    if (t < nb) partial[t] = s[t] - v;
}

__global__ void k_scan3(int* __restrict__ row_start, const int* __restrict__ partial,
                        int n, int total) {
    int i = blockIdx.x * 256 + threadIdx.x;
    if (i < n) row_start[i] += partial[i >> 10];
    if (i == 0) row_start[n] = total;
}

__global__ void k_fill(const int* __restrict__ src, const int* __restrict__ dst,
                       const int* __restrict__ row_start, int* __restrict__ fill,
                       int* __restrict__ csr_src, int E, int n) {
    int i = blockIdx.x * 256 + threadIdx.x;
    int total = E + n;
    if (i >= total) return;
    int s, d;
    if (i < E) { s = src[i]; d = dst[i]; }
    else       { s = d = i - E; }
    int pos = row_start[d] + atomicAdd(&fill[d], 1);
    csr_src[pos] = s;
}

// ---------------- weight decompose ----------------
// bf16 pair (layer 1):
__global__ void k_wdec(const float* __restrict__ W, int N, int K,
                       unsigned short* __restrict__ Wh, unsigned short* __restrict__ Wl,
                       int NPAD, int KPAD) {
    int i = blockIdx.x * 256 + threadIdx.x;
    if (i >= NPAD * KPAD) return;
    int r = i / KPAD, k = i - r * KPAD;
    float x = (r < N && k < K) ? W[r * K + k] : 0.f;
    unsigned short h = f2bf(x);
    unsigned short l = f2bf(x - bf2f(h));
    Wh[i] = h; Wl[i] = l;
}
// fp16 pair, lo pre-scaled x2048 (layers 2/3):
__global__ void k_wdec16(const float* __restrict__ W, int N, int K,
                         unsigned short* __restrict__ Wh, unsigned short* __restrict__ Wl,
                         int NPAD, int KPAD) {
    int i = blockIdx.x * 256 + threadIdx.x;
    if (i >= NPAD * KPAD) return;
    int r = i / KPAD, k = i - r * KPAD;
    float x = (r < N && k < K) ? W[r * K + k] : 0.f;
    _Float16 h = (_Float16)x;
    _Float16 l = (_Float16)((x - (float)h) * 2048.0f);
    Wh[i] = __builtin_bit_cast(unsigned short, h);
    Wl[i] = __builtin_bit_cast(unsigned short, l);
}

// ---------------- MFMA GEMM (LDS-free): H16 = (A . W^T) * dinv, fp16 out ----------
// 512 thr = 8 waves; BM = 256; wave = 32 rows x NPAD cols.
// B-fragments loaded per-lane straight from Wh/Wl (L1/L2-resident), no LDS,
// no barriers. MODE 0: A fp32 -> bf16 hi/lo, 3 MFMA/frag. MODE 1: A fp16,
// W fp16 hi + lo*2^-11 in separate accumulators, 2 MFMA/frag.

struct A8 { f32x4 lo, hi; };

template <int NF, int LDW, int MODE, typename AT>   // NPAD = NF*16
__global__ __launch_bounds__(512, 2)
void gemm_mfma(const AT* __restrict__ A, int lda, int M, int K,
               const unsigned short* __restrict__ Wh,
               const unsigned short* __restrict__ Wl,
               const float* __restrict__ dinv,
               _Float16* __restrict__ H16, int ldh, int Nout) {
    const int tid  = threadIdx.x;
    const int wv   = tid >> 6;             // 0..7
    const int lane = tid & 63;
    const int lr   = lane & 15;
    const int kq   = lane >> 4;
    const int m0   = blockIdx.x * 256;

    int arow0 = m0 + wv * 32 + lr;       if (arow0 >= M) arow0 = M - 1;
    int arow1 = m0 + wv * 32 + 16 + lr;  if (arow1 >= M) arow1 = M - 1;
    const AT* Arow0 = A + (size_t)arow0 * lda;
    const AT* Arow1 = A + (size_t)arow1 * lda;

    // per-lane W fragment base: row lr, k-slice kq*8 (16 B per frag)
    const unsigned short* WhL = Wh + (size_t)lr * LDW + kq * 8;
    const unsigned short* WlL = Wl + (size_t)lr * LDW + kq * 8;

    auto loadA32 = [&](const AT* Arow, int s) -> A8 {
        A8 o;
        int kb = s * 32 + kq * 8;
        if (kb + 8 <= K) {
            const float* ap = (const float*)Arow + kb;
            o.lo = *(const f32x4*)ap;
            o.hi = *(const f32x4*)(ap + 4);
        } else {
#pragma unroll
            for (int i = 0; i < 4; ++i) {
                int k0 = kb + i, k1 = kb + 4 + i;
                o.lo[i] = (k0 < K) ? (float)Arow[k0] : 0.f;
                o.hi[i] = (k1 < K) ? (float)Arow[k1] : 0.f;
            }
        }
        return o;
    };
    auto loadA16 = [&](const AT* Arow, int s) -> short8 {
        int kb = s * 32 + kq * 8;
        if (kb + 8 <= K) return *(const short8*)((const unsigned short*)Arow + kb);
        short8 o;
        const unsigned short* ap = (const unsigned short*)Arow;
#pragma unroll
        for (int i = 0; i < 8; ++i) o[i] = (kb + i < K) ? (short)ap[kb + i] : (short)0;
        return o;
    };

    f32x4 acP[NF], acQ[NF], alP[NF], alQ[NF];
#pragma unroll
    for (int f = 0; f < NF; ++f) {
        acP[f] = (f32x4){0.f, 0.f, 0.f, 0.f};
        acQ[f] = (f32x4){0.f, 0.f, 0.f, 0.f};
        alP[f] = (f32x4){0.f, 0.f, 0.f, 0.f};
        alQ[f] = (f32x4){0.f, 0.f, 0.f, 0.f};
    }

    constexpr int nsteps = LDW / 32;

    for (int s = 0; s < nsteps; ++s) {
        const unsigned short* wph = WhL + s * 32;
        const unsigned short* wpl = WlL + s * 32;

        if constexpr (MODE == 0) {
            A8 a0 = loadA32(Arow0, s);
            A8 a1 = loadA32(Arow1, s);
            float av0[8], av1[8];
#pragma unroll
            for (int i = 0; i < 4; ++i) {
                av0[i] = a0.lo[i]; av0[4 + i] = a0.hi[i];
                av1[i] = a1.lo[i]; av1[4 + i] = a1.hi[i];
            }
            short8 a0hi, a0lo, a1hi, a1lo;
#pragma unroll
            for (int i = 0; i < 8; ++i) {
                unsigned short h0 = f2bf(av0[i]);
                a0hi[i] = (short)h0; a0lo[i] = (short)f2bf(av0[i] - bf2f(h0));
                unsigned short h1 = f2bf(av1[i]);
                a1hi[i] = (short)h1; a1lo[i] = (short)f2bf(av1[i] - bf2f(h1));
            }
#pragma unroll
            for (int f = 0; f < NF; ++f) {
                short8 bh = *(const short8*)(wph + (size_t)f * 16 * LDW);
                short8 bl = *(const short8*)(wpl + (size_t)f * 16 * LDW);
                acP[f] = __builtin_amdgcn_mfma_f32_16x16x32_bf16(a0hi, bh, acP[f], 0, 0, 0);
                acP[f] = __builtin_amdgcn_mfma_f32_16x16x32_bf16(a0hi, bl, acP[f], 0, 0, 0);
                acP[f] = __builtin_amdgcn_mfma_f32_16x16x32_bf16(a0lo, bh, acP[f], 0, 0, 0);
                acQ[f] = __builtin_amdgcn_mfma_f32_16x16x32_bf16(a1hi, bh, acQ[f], 0, 0, 0);
                acQ[f] = __builtin_amdgcn_mfma_f32_16x16x32_bf16(a1hi, bl, acQ[f], 0, 0, 0);
                acQ[f] = __builtin_amdgcn_mfma_f32_16x16x32_bf16(a1lo, bh, acQ[f], 0, 0, 0);
            }
        } else {
            f16x8 a0 = __builtin_bit_cast(f16x8, loadA16(Arow0, s));
            f16x8 a1 = __builtin_bit_cast(f16x8, loadA16(Arow1, s));
#pragma unroll
            for (int f = 0; f < NF; ++f) {
                f16x8 bh = __builtin_bit_cast(f16x8, *(const short8*)(wph + (size_t)f * 16 * LDW));
                f16x8 bl = __builtin_bit_cast(f16x8, *(const short8*)(wpl + (size_t)f * 16 * LDW));
                acP[f] = __builtin_amdgcn_mfma_f32_16x16x32_f16(a0, bh, acP[f], 0, 0, 0);
                alP[f] = __builtin_amdgcn_mfma_f32_16x16x32_f16(a0, bl, alP[f], 0, 0, 0);
                acQ[f] = __builtin_amdgcn_mfma_f32_16x16x32_f16(a1, bh, acQ[f], 0, 0, 0);
                alQ[f] = __builtin_amdgcn_mfma_f32_16x16x32_f16(a1, bl, alQ[f], 0, 0, 0);
            }
        }
    }

    // ---- store: D row=(lane>>4)*4+j, col=lane&15; scale dinv, cast fp16 ----
    {
        const int rbase = m0 + wv * 32 + kq * 4;
        float dv[4];
#pragma unroll
        for (int j = 0; j < 4; ++j) {
            int row = rbase + j;
            dv[j] = (row < M) ? dinv[row] : 0.f;
        }
#pragma unroll
        for (int f = 0; f < NF; ++f) {
            int col = f * 16 + lr;
            if (col >= Nout) continue;
#pragma unroll
            for (int j = 0; j < 4; ++j) {
                int row = rbase + j;
                if (row >= M) continue;
                float v = acP[f][j];
                if constexpr (MODE == 1) v += alP[f][j] * (1.0f / 2048.0f);
                H16[(size_t)row * ldh + col] = (_Float16)(v * dv[j]);
            }
        }
    }
    {
        const int rbase = m0 + wv * 32 + 16 + kq * 4;
        float dv[4];
#pragma unroll
        for (int j = 0; j < 4; ++j) {
            int row = rbase + j;
            dv[j] = (row < M) ? dinv[row] : 0.f;
        }
#pragma unroll
        for (int f = 0; f < NF; ++f) {
            int col = f * 16 + lr;
            if (col >= Nout) continue;
#pragma unroll
            for (int j = 0; j < 4; ++j) {
                int row = rbase + j;
                if (row >= M) continue;
                float v = acQ[f][j];
                if constexpr (MODE == 1) v += alQ[f][j] * (1.0f / 2048.0f);
                H16[(size_t)row * ldh + col] = (_Float16)(v * dv[j]);
            }
        }
    }
}

// ---------------- aggregation: out = dinv[d] * sum_e h16[src_e] + b -----------------
// fp16 gather, 4 features (8 B) per lane; edge loop 4-deep software-pipelined.

template <int F, bool RELU>
__global__ __launch_bounds__(256)
void agg_f16(const _Float16* __restrict__ h, const int* __restrict__ row_start,
             const int* __restrict__ csr_src, const float* __restrict__ dinv,
             const float* __restrict__ bias, _Float16* __restrict__ out, int n,
             int ldo) {
    constexpr int LPN = F / 4;
    constexpr int NPW = 64 / LPN;
    int wave = blockIdx.x * 4 + (threadIdx.x >> 6);
    int lane = threadIdx.x & 63;
    int sub  = lane / LPN;
    int fi   = lane - sub * LPN;
    int node = wave * NPW + sub;
    if (sub >= NPW || node >= n) return;
    int f = fi * 4;
    const _Float16* hf = h + f;

    f32x4 acc = {0.f, 0.f, 0.f, 0.f};
    int e0 = row_start[node], e1 = row_start[node + 1];
    int e = e0;
    for (; e + 4 <= e1; e += 4) {
        int s0 = csr_src[e + 0];
        int s1 = csr_src[e + 1];
        int s2 = csr_src[e + 2];
        int s3 = csr_src[e + 3];
        f16x4 v0 = *(const f16x4*)&hf[(size_t)s0 * F];
        f16x4 v1 = *(const f16x4*)&hf[(size_t)s1 * F];
        f16x4 v2 = *(const f16x4*)&hf[(size_t)s2 * F];
        f16x4 v3 = *(const f16x4*)&hf[(size_t)s3 * F];
        acc += __builtin_convertvector(v0, f32x4);
        acc += __builtin_convertvector(v1, f32x4);
        acc += __builtin_convertvector(v2, f32x4);
        acc += __builtin_convertvector(v3, f32x4);
    }
    for (; e < e1; ++e) {
        int s = csr_src[e];
        f16x4 v = *(const f16x4*)&hf[(size_t)s * F];
        acc += __builtin_convertvector(v, f32x4);
    }
    float dn = dinv[node];
    f32x4 b4 = *(const f32x4*)&bias[f];
    acc = acc * dn + b4;
    if (RELU) {
#pragma unroll
        for (int j = 0; j < 4; ++j) acc[j] = fmaxf(acc[j], 0.f);
    }
    f16x4 o;
#pragma unroll
    for (int j = 0; j < 4; ++j) o[j] = (_Float16)acc[j];
    *(f16x4*)&out[(size_t)node * ldo + f] = o;
}

// ---------------- tiny layer-4 helpers ----------------

__global__ void gemm_small(const _Float16* __restrict__ A, const float* __restrict__ B,
                           const float* __restrict__ dinv, float* __restrict__ C,
                           int M, int K) {
    int m = blockIdx.x * 256 + threadIdx.x;
    if (m >= M) return;
    float a0 = 0.f, a1 = 0.f, a2 = 0.f;
    for (int k = 0; k < K; ++k) {
        float a = (float)A[(size_t)m * K + k];
        a0 += a * B[0 * K + k];
        a1 += a * B[1 * K + k];
        a2 += a * B[2 * K + k];
    }
    float dv = dinv[m];
    C[(size_t)m * 3 + 0] = a0 * dv;
    C[(size_t)m * 3 + 1] = a1 * dv;
    C[(size_t)m * 3 + 2] = a2 * dv;
}

__global__ void agg_f3(const float* __restrict__ h, const int* __restrict__ row_start,
                       const int* __restrict__ csr_src, const float* __restrict__ dinv,
                       const float* __restrict__ bias, float* __restrict__ out, int n) {
    int i = blockIdx.x * 256 + threadIdx.x;
    if (i >= n * 3) return;
    int node = i / 3;
    int f = i - node * 3;
    float acc = 0.f;
    int e1 = row_start[node + 1];
    for (int e = row_start[node]; e < e1; ++e) {
        int s = csr_src[e];
        acc += h[(size_t)s * 3 + f];
    }
    out[i] = acc * dinv[node] + bias[f];
}

// ---------------------------------------------------------------------------

extern "C" void kernel_launch(void* const* d_in, const int* in_sizes, int n_in,
                              void* d_out, int out_size, void* d_ws, size_t ws_size,
                              hipStream_t stream) {
    const float* x   = (const float*)d_in[0];
    const int*   ei  = (const int*)d_in[1];
    const float* W1  = (const float*)d_in[2];
    const float* b1  = (const float*)d_in[3];
    const float* W1b = (const float*)d_in[4];
    const float* b1b = (const float*)d_in[5];
    const float* W2b = (const float*)d_in[6];
    const float* b2b = (const float*)d_in[7];
    const float* W2  = (const float*)d_in[8];
    const float* b2  = (const float*)d_in[9];
    float* out = (float*)d_out;

    const int F_IN = 500, H1 = 200, H2 = 100, H3 = 40;
    const int N = in_sizes[0] / F_IN;
    const int E = in_sizes[1] / 2;
    const int* src = ei;
    const int* dst = ei + E;

    size_t off = 0;
    auto alloc = [&](size_t bytes) -> void* {
        void* p = (char*)d_ws + off;
        off += (bytes + 255) & ~(size_t)255;
        return p;
    };
    int*   cnt       = (int*)  alloc((size_t)N * 4);
    int*   row_start = (int*)  alloc((size_t)(N + 1) * 4);
    int*   fill      = (int*)  alloc((size_t)N * 4);
    int*   partial   = (int*)  alloc(128 * 4);
    float* dinv      = (float*)alloc((size_t)N * 4);
    int*   csr_src   = (int*)  alloc((size_t)(E + N) * 4);
    unsigned short* wh1 = (unsigned short*)alloc(208 * 512 * 2);
    unsigned short* wl1 = (unsigned short*)alloc(208 * 512 * 2);
    unsigned short* wh2 = (unsigned short*)alloc(112 * 224 * 2);
    unsigned short* wl2 = (unsigned short*)alloc(112 * 224 * 2);
    unsigned short* wh3 = (unsigned short*)alloc(48 * 128 * 2);
    unsigned short* wl3 = (unsigned short*)alloc(48 * 128 * 2);
    _Float16* h16   = (_Float16*)alloc((size_t)N * H1 * 2);  // gemm outputs (scaled fp16)
    _Float16* act16 = (_Float16*)alloc((size_t)N * H1 * 2);  // agg outputs (fp16)
    float*    bufC  = (float*)   alloc((size_t)N * 3 * 4);   // layer-4 gemm out

    int gN  = (N + 255) / 256;
    int gE  = (E + 255) / 256;
    int gEN = (E + N + 255) / 256;
    int nb  = (N + 1023) / 1024;

    // --- CSR build ---
    k_init <<<gN, 256, 0, stream>>>(cnt, fill, N);
    k_count<<<gE, 256, 0, stream>>>(dst, cnt, E);
    k_scan1<<<nb, 256, 0, stream>>>(cnt, row_start, partial, dinv, N);
    k_scan2<<<1, 128, 0, stream>>>(partial, nb);
    k_scan3<<<gN, 256, 0, stream>>>(row_start, partial, N, E + N);
    k_fill <<<gEN, 256, 0, stream>>>(src, dst, row_start, fill, csr_src, E, N);

    // --- weight decomposition ---
    k_wdec  <<<(208 * 512 + 255) / 256, 256, 0, stream>>>(W1,  H1, F_IN, wh1, wl1, 208, 512);
    k_wdec16<<<(112 * 224 + 255) / 256, 256, 0, stream>>>(W1b, H2, H1,   wh2, wl2, 112, 224);
    k_wdec16<<<( 48 * 128 + 255) / 256, 256, 0, stream>>>(W2b, H3, H2,   wh3, wl3,  48, 128);

    const int gG = (N + 255) / 256;   // BM = 256

    // --- layer 1 ---
    gemm_mfma<13, 512, 0, float><<<gG, 512, 0, stream>>>(x, F_IN, N, F_IN, wh1, wl1,
                                                         dinv, h16, H1, H1);
    agg_f16<200, true><<<(N + 3) / 4, 256, 0, stream>>>(h16, row_start, csr_src, dinv,
                                                        b1, act16, N, 200);
    // --- layer 2 ---
    gemm_mfma<7, 224, 1, _Float16><<<gG, 512, 0, stream>>>(act16, 200, N, H1, wh2, wl2,
                                                           dinv, h16, H2, H2);
    agg_f16<100, true><<<(N / 2 + 3) / 4, 256, 0, stream>>>(h16, row_start, csr_src, dinv,
                                                            b1b, act16, N, 112);
    // --- layer 3 (A stride 112 keeps 16-B loads aligned) ---
    gemm_mfma<3, 128, 1, _Float16><<<gG, 512, 0, stream>>>(act16, 112, N, H2, wh3, wl3,
                                                           dinv, h16, H3, H3);
    {
        int waves = (N + 5) / 6, blocks = (waves + 3) / 4;
        agg_f16<40, true><<<blocks, 256, 0, stream>>>(h16, row_start, csr_src, dinv,
                                                      b2b, act16, N, 40);
    }
    // --- layer 4 ---
    gemm_small<<<(N + 255) / 256, 256, 0, stream>>>(act16, W2, dinv, bufC, N, H3);
    agg_f3<<<(N * 3 + 255) / 256, 256, 0, stream>>>(bufC, row_start, csr_src, dinv,
                                                    b2, out, N);
}

// Round 10
// 603.583 us; speedup vs baseline: 1.2938x; 1.2938x over previous
//
#include <hip/hip_runtime.h>

// ---------------------------------------------------------------------------
// GCN 4-layer inference.
//  - GEMMs (layers 1-3): fp16 MFMA, W = wh16 + wl16*2^-11 (near-exact, 2 mfma
//    per frag). Layer-1 A converted fp32->fp16 in-register (error ~2^-12).
//    8 waves = 4 row-groups x 2 col-groups (col-split halves LDS re-reads);
//    wave = 32 rows x ~NPAD/2 cols. Double-buffered LDS, one barrier/step,
//    W staged via global_load_lds (DMA, pre-swizzled source), A prefetched.
//  - Activations between layers fp16.
//  - Aggregation: CSR gather of fp16 rows, 4-deep software-pipelined.
// ---------------------------------------------------------------------------

#define DEV __device__ __forceinline__

typedef __attribute__((ext_vector_type(8))) short short8;
typedef __attribute__((ext_vector_type(8))) _Float16 f16x8;
typedef __attribute__((ext_vector_type(4))) float f32x4;
typedef __attribute__((ext_vector_type(4))) _Float16 f16x4;

DEV void gload_lds16(const void* g, void* l) {     // 16-B DMA global -> LDS
    __builtin_amdgcn_global_load_lds(
        (const __attribute__((address_space(1))) unsigned int*)g,
        (__attribute__((address_space(3))) unsigned int*)l, 16, 0, 0);
}

// ---------------- CSR build ----------------

__global__ void k_init(int* __restrict__ cnt, int* __restrict__ fill, int n) {
    int i = blockIdx.x * 256 + threadIdx.x;
    if (i < n) { cnt[i] = 1; fill[i] = 0; }   // 1 = self-loop
}

__global__ void k_count(const int* __restrict__ dst, int* __restrict__ cnt, int E) {
    int e = blockIdx.x * 256 + threadIdx.x;
    if (e < E) atomicAdd(&cnt[dst[e]], 1);
}

__global__ void k_scan1(const int* __restrict__ cnt, int* __restrict__ row_start,
                        int* __restrict__ partial, float* __restrict__ dinv, int n) {
    __shared__ int sdata[256];
    int base = blockIdx.x * 1024;
    int t = threadIdx.x;
    int v[4]; int sum = 0;
#pragma unroll
    for (int j = 0; j < 4; ++j) {
        int idx = base + t * 4 + j;
        v[j] = (idx < n) ? cnt[idx] : 0;
        if (idx < n) dinv[idx] = rsqrtf((float)v[j]);
        sum += v[j];
    }
    sdata[t] = sum;
    __syncthreads();
    for (int off = 1; off < 256; off <<= 1) {
        int x = (t >= off) ? sdata[t - off] : 0;
        __syncthreads();
        sdata[t] += x;
        __syncthreads();
    }
    int excl = sdata[t] - sum;
#pragma unroll
    for (int j = 0; j < 4; ++j) {
        int idx = base + t * 4 + j;
        if (idx < n) row_start[idx] = excl;
        excl += v[j];
    }
    if (t == 255) partial[blockIdx.x] = sdata[255];
}

__global__ void k_scan2(int* __restrict__ partial, int nb) {
    __shared__ int s[128];
    int t = threadIdx.x;
    int v = (t < nb) ? partial[t] : 0;
    s[t] = v;
    __syncthreads();
    for (int off = 1; off < 128; off <<= 1) {
        int x = (t >= off) ? s[t - off] : 0;
        __syncthreads();
        s[t] += x;
        __syncthreads();
    }
    if (t < nb) partial[t] = s[t] - v;
}

__global__ void k_scan3(int* __restrict__ row_start, const int* __restrict__ partial,
                        int n, int total) {
    int i = blockIdx.x * 256 + threadIdx.x;
    if (i < n) row_start[i] += partial[i >> 10];
    if (i == 0) row_start[n] = total;
}

__global__ void k_fill(const int* __restrict__ src, const int* __restrict__ dst,
                       const int* __restrict__ row_start, int* __restrict__ fill,
                       int* __restrict__ csr_src, int E, int n) {
    int i = blockIdx.x * 256 + threadIdx.x;
    int total = E + n;
    if (i >= total) return;
    int s, d;
    if (i < E) { s = src[i]; d = dst[i]; }
    else       { s = d = i - E; }
    int pos = row_start[d] + atomicAdd(&fill[d], 1);
    csr_src[pos] = s;
}

// ---------------- weight decompose: fp16 pair, lo pre-scaled x2048 ----------------

__global__ void k_wdec16(const float* __restrict__ W, int N, int K,
                         unsigned short* __restrict__ Wh, unsigned short* __restrict__ Wl,
                         int NPAD, int KPAD) {
    int i = blockIdx.x * 256 + threadIdx.x;
    if (i >= NPAD * KPAD) return;
    int r = i / KPAD, k = i - r * KPAD;
    float x = (r < N && k < K) ? W[r * K + k] : 0.f;
    _Float16 h = (_Float16)x;
    _Float16 l = (_Float16)((x - (float)h) * 2048.0f);
    Wh[i] = __builtin_bit_cast(unsigned short, h);
    Wl[i] = __builtin_bit_cast(unsigned short, l);
}

// ---------------- MFMA GEMM: H16[m][c] = (A[m][:] . W[c][:]) * dinv[m] ----------
// 512 thr = 8 waves = 4 row-groups x 2 col-groups. BM = 128 (32 rows/wave).
// Per wave: 2 A-frags x FC B-frag-pairs. W fp16 hi + lo*2^-11, separate accs.
// MODE 0: A fp32 -> cvt fp16 in-register. MODE 1: A fp16 direct.

struct A8 { f32x4 lo, hi; };

template <int NF, int MODE, typename AT>   // NPAD = NF*16
__global__ __launch_bounds__(512, 2)
void gemm_mfma(const AT* __restrict__ A, int lda, int M, int K,
               const unsigned short* __restrict__ Wh,
               const unsigned short* __restrict__ Wl, int ldw,
               const float* __restrict__ dinv,
               _Float16* __restrict__ H16, int ldh, int Nout) {
    constexpr int NPAD = NF * 16;
    constexpr int HBUF = NPAD * 64;        // bytes per half (hi or lo)
    constexpr int BUFB = 2 * HBUF;         // one K-step buffer
    constexpr int CH   = NPAD * 4;         // 16-B chunks per half
    constexpr int CH2  = 2 * CH;
    constexpr int NISS = CH2 / 64;         // wave-issues per step
    constexpr int FC   = (NF + 1) / 2;     // frags per col-group
    __shared__ char lds[2 * BUFB];

    const int tid  = threadIdx.x;
    const int wv   = tid >> 6;             // 0..7
    const int rg   = wv >> 1;              // row-group 0..3
    const int cg   = wv & 1;               // col-group 0..1
    const int lane = tid & 63;
    const int lr   = lane & 15;
    const int kq   = lane >> 4;
    const int m0   = blockIdx.x * 128;
    const int f0   = cg * FC;

    int arow0 = m0 + rg * 32 + lr;       if (arow0 >= M) arow0 = M - 1;
    int arow1 = m0 + rg * 32 + 16 + lr;  if (arow1 >= M) arow1 = M - 1;
    const AT* Arow0 = A + (size_t)arow0 * lda;
    const AT* Arow1 = A + (size_t)arow1 * lda;

    auto stageW = [&](int s, int bufsel) {
        const int kb = s * 32;
        char* base = lds + bufsel * BUFB;
        for (int i = wv; i < NISS; i += 8) {
            int c  = i * 64 + lane;
            int h  = (c >= CH) ? 1 : 0;
            int cc = c - h * CH;
            int r  = cc >> 2;
            int sl = cc & 3;
            int gs = sl ^ (r & 3);         // involutory slot swizzle (source side)
            const unsigned short* gp = (h ? Wl : Wh) + (size_t)r * ldw + kb + gs * 8;
            gload_lds16(gp, base + i * 1024);
        }
    };

    auto loadA32 = [&](const AT* Arow, int s) -> A8 {
        A8 o;
        int kb = s * 32 + kq * 8;
        if (kb + 8 <= K) {
            const float* ap = (const float*)Arow + kb;
            o.lo = *(const f32x4*)ap;
            o.hi = *(const f32x4*)(ap + 4);
        } else {
#pragma unroll
            for (int i = 0; i < 4; ++i) {
                int k0 = kb + i, k1 = kb + 4 + i;
                o.lo[i] = (k0 < K) ? (float)Arow[k0] : 0.f;
                o.hi[i] = (k1 < K) ? (float)Arow[k1] : 0.f;
            }
        }
        return o;
    };
    auto loadA16 = [&](const AT* Arow, int s) -> short8 {
        int kb = s * 32 + kq * 8;
        if (kb + 8 <= K) return *(const short8*)((const unsigned short*)Arow + kb);
        short8 o;
        const unsigned short* ap = (const unsigned short*)Arow;
#pragma unroll
        for (int i = 0; i < 8; ++i) o[i] = (kb + i < K) ? (short)ap[kb + i] : (short)0;
        return o;
    };
    auto cvtA = [&](const A8& a) -> f16x8 {
        f16x8 o;
#pragma unroll
        for (int i = 0; i < 4; ++i) {
            o[i]     = (_Float16)a.lo[i];
            o[4 + i] = (_Float16)a.hi[i];
        }
        return o;
    };

    f32x4 acP[FC], alP[FC], acQ[FC], alQ[FC];
#pragma unroll
    for (int ff = 0; ff < FC; ++ff) {
        acP[ff] = (f32x4){0.f, 0.f, 0.f, 0.f};
        alP[ff] = (f32x4){0.f, 0.f, 0.f, 0.f};
        acQ[ff] = (f32x4){0.f, 0.f, 0.f, 0.f};
        alQ[ff] = (f32x4){0.f, 0.f, 0.f, 0.f};
    }

    const int nsteps = ldw / 32;

    // ---- prologue ----
    stageW(0, 0);
    A8 a0c{}, a1c{}; short8 h0c{}, h1c{};
    if constexpr (MODE == 0) { a0c = loadA32(Arow0, 0); a1c = loadA32(Arow1, 0); }
    else                     { h0c = loadA16(Arow0, 0); h1c = loadA16(Arow1, 0); }
    __syncthreads();

    const int ro = lr * 64 + ((kq ^ (lr & 3)) << 4);   // swizzled read offset

    for (int s = 0; s < nsteps; ++s) {
        const char* bb = lds + (s & 1) * BUFB;
        const bool more = (s + 1 < nsteps);

        if (more) stageW(s + 1, (s + 1) & 1);
        A8 a0n{}, a1n{}; short8 h0n{}, h1n{};
        if (more) {
            if constexpr (MODE == 0) { a0n = loadA32(Arow0, s + 1); a1n = loadA32(Arow1, s + 1); }
            else                     { h0n = loadA16(Arow0, s + 1); h1n = loadA16(Arow1, s + 1); }
        }

        f16x8 a0, a1;
        if constexpr (MODE == 0) { a0 = cvtA(a0c); a1 = cvtA(a1c); }
        else { a0 = __builtin_bit_cast(f16x8, h0c); a1 = __builtin_bit_cast(f16x8, h1c); }

#pragma unroll
        for (int ff = 0; ff < FC; ++ff) {
            int f = f0 + ff;
            if (f < NF) {
                f16x8 bh = __builtin_bit_cast(f16x8, *(const short8*)(bb + f * 1024 + ro));
                f16x8 bl = __builtin_bit_cast(f16x8, *(const short8*)(bb + HBUF + f * 1024 + ro));
                acP[ff] = __builtin_amdgcn_mfma_f32_16x16x32_f16(a0, bh, acP[ff], 0, 0, 0);
                alP[ff] = __builtin_amdgcn_mfma_f32_16x16x32_f16(a0, bl, alP[ff], 0, 0, 0);
                acQ[ff] = __builtin_amdgcn_mfma_f32_16x16x32_f16(a1, bh, acQ[ff], 0, 0, 0);
                alQ[ff] = __builtin_amdgcn_mfma_f32_16x16x32_f16(a1, bl, alQ[ff], 0, 0, 0);
            }
        }

        __syncthreads();
        if constexpr (MODE == 0) { a0c = a0n; a1c = a1n; }
        else                     { h0c = h0n; h1c = h1n; }
    }

    // ---- store: D row=(lane>>4)*4+j, col=lane&15; scale dinv, cast fp16 ----
    {
        const int rbase = m0 + rg * 32 + kq * 4;
        float dv[4];
#pragma unroll
        for (int j = 0; j < 4; ++j) {
            int row = rbase + j;
            dv[j] = (row < M) ? dinv[row] : 0.f;
        }
#pragma unroll
        for (int ff = 0; ff < FC; ++ff) {
            int f = f0 + ff;
            if (f >= NF) continue;
            int col = f * 16 + lr;
            if (col >= Nout) continue;
#pragma unroll
            for (int j = 0; j < 4; ++j) {
                int row = rbase + j;
                if (row >= M) continue;
                float v = acP[ff][j] + alP[ff][j] * (1.0f / 2048.0f);
                H16[(size_t)row * ldh + col] = (_Float16)(v * dv[j]);
            }
        }
    }
    {
        const int rbase = m0 + rg * 32 + 16 + kq * 4;
        float dv[4];
#pragma unroll
        for (int j = 0; j < 4; ++j) {
            int row = rbase + j;
            dv[j] = (row < M) ? dinv[row] : 0.f;
        }
#pragma unroll
        for (int ff = 0; ff < FC; ++ff) {
            int f = f0 + ff;
            if (f >= NF) continue;
            int col = f * 16 + lr;
            if (col >= Nout) continue;
#pragma unroll
            for (int j = 0; j < 4; ++j) {
                int row = rbase + j;
                if (row >= M) continue;
                float v = acQ[ff][j] + alQ[ff][j] * (1.0f / 2048.0f);
                H16[(size_t)row * ldh + col] = (_Float16)(v * dv[j]);
            }
        }
    }
}

// ---------------- aggregation: out = dinv[d] * sum_e h16[src_e] + b -----------------
// fp16 gather, 4 features (8 B) per lane; edge loop 4-deep software-pipelined.

template <int F, bool RELU>
__global__ __launch_bounds__(256)
void agg_f16(const _Float16* __restrict__ h, const int* __restrict__ row_start,
             const int* __restrict__ csr_src, const float* __restrict__ dinv,
             const float* __restrict__ bias, _Float16* __restrict__ out, int n,
             int ldo) {
    constexpr int LPN = F / 4;
    constexpr int NPW = 64 / LPN;
    int wave = blockIdx.x * 4 + (threadIdx.x >> 6);
    int lane = threadIdx.x & 63;
    int sub  = lane / LPN;
    int fi   = lane - sub * LPN;
    int node = wave * NPW + sub;
    if (sub >= NPW || node >= n) return;
    int f = fi * 4;
    const _Float16* hf = h + f;

    f32x4 acc = {0.f, 0.f, 0.f, 0.f};
    int e0 = row_start[node], e1 = row_start[node + 1];
    int e = e0;
    for (; e + 4 <= e1; e += 4) {
        int s0 = csr_src[e + 0];
        int s1 = csr_src[e + 1];
        int s2 = csr_src[e + 2];
        int s3 = csr_src[e + 3];
        f16x4 v0 = *(const f16x4*)&hf[(size_t)s0 * F];
        f16x4 v1 = *(const f16x4*)&hf[(size_t)s1 * F];
        f16x4 v2 = *(const f16x4*)&hf[(size_t)s2 * F];
        f16x4 v3 = *(const f16x4*)&hf[(size_t)s3 * F];
        acc += __builtin_convertvector(v0, f32x4);
        acc += __builtin_convertvector(v1, f32x4);
        acc += __builtin_convertvector(v2, f32x4);
        acc += __builtin_convertvector(v3, f32x4);
    }
    for (; e < e1; ++e) {
        int s = csr_src[e];
        f16x4 v = *(const f16x4*)&hf[(size_t)s * F];
        acc += __builtin_convertvector(v, f32x4);
    }
    float dn = dinv[node];
    f32x4 b4 = *(const f32x4*)&bias[f];
    acc = acc * dn + b4;
    if (RELU) {
#pragma unroll
        for (int j = 0; j < 4; ++j) acc[j] = fmaxf(acc[j], 0.f);
    }
    f16x4 o;
#pragma unroll
    for (int j = 0; j < 4; ++j) o[j] = (_Float16)acc[j];
    *(f16x4*)&out[(size_t)node * ldo + f] = o;
}

// ---------------- tiny layer-4 helpers ----------------

__global__ void gemm_small(const _Float16* __restrict__ A, const float* __restrict__ B,
                           const float* __restrict__ dinv, float* __restrict__ C,
                           int M, int K) {
    int m = blockIdx.x * 256 + threadIdx.x;
    if (m >= M) return;
    float a0 = 0.f, a1 = 0.f, a2 = 0.f;
    for (int k = 0; k < K; ++k) {
        float a = (float)A[(size_t)m * K + k];
        a0 += a * B[0 * K + k];
        a1 += a * B[1 * K + k];
        a2 += a * B[2 * K + k];
    }
    float dv = dinv[m];
    C[(size_t)m * 3 + 0] = a0 * dv;
    C[(size_t)m * 3 + 1] = a1 * dv;
    C[(size_t)m * 3 + 2] = a2 * dv;
}

__global__ void agg_f3(const float* __restrict__ h, const int* __restrict__ row_start,
                       const int* __restrict__ csr_src, const float* __restrict__ dinv,
                       const float* __restrict__ bias, float* __restrict__ out, int n) {
    int i = blockIdx.x * 256 + threadIdx.x;
    if (i >= n * 3) return;
    int node = i / 3;
    int f = i - node * 3;
    float acc = 0.f;
    int e1 = row_start[node + 1];
    for (int e = row_start[node]; e < e1; ++e) {
        int s = csr_src[e];
        acc += h[(size_t)s * 3 + f];
    }
    out[i] = acc * dinv[node] + bias[f];
}

// ---------------------------------------------------------------------------

extern "C" void kernel_launch(void* const* d_in, const int* in_sizes, int n_in,
                              void* d_out, int out_size, void* d_ws, size_t ws_size,
                              hipStream_t stream) {
    const float* x   = (const float*)d_in[0];
    const int*   ei  = (const int*)d_in[1];
    const float* W1  = (const float*)d_in[2];
    const float* b1  = (const float*)d_in[3];
    const float* W1b = (const float*)d_in[4];
    const float* b1b = (const float*)d_in[5];
    const float* W2b = (const float*)d_in[6];
    const float* b2b = (const float*)d_in[7];
    const float* W2  = (const float*)d_in[8];
    const float* b2  = (const float*)d_in[9];
    float* out = (float*)d_out;

    const int F_IN = 500, H1 = 200, H2 = 100, H3 = 40;
    const int N = in_sizes[0] / F_IN;
    const int E = in_sizes[1] / 2;
    const int* src = ei;
    const int* dst = ei + E;

    size_t off = 0;
    auto alloc = [&](size_t bytes) -> void* {
        void* p = (char*)d_ws + off;
        off += (bytes + 255) & ~(size_t)255;
        return p;
    };
    int*   cnt       = (int*)  alloc((size_t)N * 4);
    int*   row_start = (int*)  alloc((size_t)(N + 1) * 4);
    int*   fill      = (int*)  alloc((size_t)N * 4);
    int*   partial   = (int*)  alloc(128 * 4);
    float* dinv      = (float*)alloc((size_t)N * 4);
    int*   csr_src   = (int*)  alloc((size_t)(E + N) * 4);
    unsigned short* wh1 = (unsigned short*)alloc(208 * 512 * 2);
    unsigned short* wl1 = (unsigned short*)alloc(208 * 512 * 2);
    unsigned short* wh2 = (unsigned short*)alloc(112 * 224 * 2);
    unsigned short* wl2 = (unsigned short*)alloc(112 * 224 * 2);
    unsigned short* wh3 = (unsigned short*)alloc(48 * 128 * 2);
    unsigned short* wl3 = (unsigned short*)alloc(48 * 128 * 2);
    _Float16* h16   = (_Float16*)alloc((size_t)N * H1 * 2);  // gemm outputs (scaled fp16)
    _Float16* act16 = (_Float16*)alloc((size_t)N * H1 * 2);  // agg outputs (fp16)
    float*    bufC  = (float*)   alloc((size_t)N * 3 * 4);   // layer-4 gemm out

    int gN  = (N + 255) / 256;
    int gE  = (E + 255) / 256;
    int gEN = (E + N + 255) / 256;
    int nb  = (N + 1023) / 1024;

    // --- CSR build ---
    k_init <<<gN, 256, 0, stream>>>(cnt, fill, N);
    k_count<<<gE, 256, 0, stream>>>(dst, cnt, E);
    k_scan1<<<nb, 256, 0, stream>>>(cnt, row_start, partial, dinv, N);
    k_scan2<<<1, 128, 0, stream>>>(partial, nb);
    k_scan3<<<gN, 256, 0, stream>>>(row_start, partial, N, E + N);
    k_fill <<<gEN, 256, 0, stream>>>(src, dst, row_start, fill, csr_src, E, N);

    // --- weight decomposition (fp16 hi/lo for all layers) ---
    k_wdec16<<<(208 * 512 + 255) / 256, 256, 0, stream>>>(W1,  H1, F_IN, wh1, wl1, 208, 512);
    k_wdec16<<<(112 * 224 + 255) / 256, 256, 0, stream>>>(W1b, H2, H1,   wh2, wl2, 112, 224);
    k_wdec16<<<( 48 * 128 + 255) / 256, 256, 0, stream>>>(W2b, H3, H2,   wh3, wl3,  48, 128);

    const int gG = (N + 127) / 128;   // BM = 128

    // --- layer 1 ---
    gemm_mfma<13, 0, float><<<gG, 512, 0, stream>>>(x, F_IN, N, F_IN, wh1, wl1, 512,
                                                    dinv, h16, H1, H1);
    agg_f16<200, true><<<(N + 3) / 4, 256, 0, stream>>>(h16, row_start, csr_src, dinv,
                                                        b1, act16, N, 200);
    // --- layer 2 ---
    gemm_mfma<7, 1, _Float16><<<gG, 512, 0, stream>>>(act16, 200, N, H1, wh2, wl2, 224,
                                                      dinv, h16, H2, H2);
    agg_f16<100, true><<<(N / 2 + 3) / 4, 256, 0, stream>>>(h16, row_start, csr_src, dinv,
                                                            b1b, act16, N, 112);
    // --- layer 3 (A stride 112 keeps 16-B loads aligned) ---
    gemm_mfma<3, 1, _Float16><<<gG, 512, 0, stream>>>(act16, 112, N, H2, wh3, wl3, 128,
                                                      dinv, h16, H3, H3);
    {
        int waves = (N + 5) / 6, blocks = (waves + 3) / 4;
        agg_f16<40, true><<<blocks, 256, 0, stream>>>(h16, row_start, csr_src, dinv,
                                                      b2b, act16, N, 40);
    }
    // --- layer 4 ---
    gemm_small<<<(N + 255) / 256, 256, 0, stream>>>(act16, W2, dinv, bufC, N, H3);
    agg_f3<<<(N * 3 + 255) / 256, 256, 0, stream>>>(bufC, row_start, csr_src, dinv,
                                                    b2, out, N);
}

// Round 11
// 567.957 us; speedup vs baseline: 1.3749x; 1.0627x over previous
//
#include <hip/hip_runtime.h>

// ---------------------------------------------------------------------------
// GCN 4-layer inference.
//  - GEMMs: resident-W design. The whole weight tile (col-half for layer 1)
//    is staged to LDS ONCE in a prologue (global_load_lds DMA, pre-swizzled
//    source), then the K-loop runs with ZERO barriers: per-lane A loads +
//    swizzled ds_reads + MFMAs, compiler-pipelined.
//    Layer 1: W fp16-single (224-pad, 2 col-halves of 112, 114.7KB LDS).
//    Layers 2/3: W fp16 hi + lo*2^-11 resident in full (100KB / 24KB).
//  - Activations between layers fp16.
//  - Aggregation: CSR gather of fp16 rows, 4-deep software-pipelined.
// ---------------------------------------------------------------------------

#define DEV __device__ __forceinline__

typedef __attribute__((ext_vector_type(8))) short short8;
typedef __attribute__((ext_vector_type(8))) _Float16 f16x8;
typedef __attribute__((ext_vector_type(4))) float f32x4;
typedef __attribute__((ext_vector_type(4))) _Float16 f16x4;

DEV void gload_lds16(const void* g, void* l) {     // 16-B DMA global -> LDS
    __builtin_amdgcn_global_load_lds(
        (const __attribute__((address_space(1))) unsigned int*)g,
        (__attribute__((address_space(3))) unsigned int*)l, 16, 0, 0);
}

// ---------------- CSR build ----------------

__global__ void k_init(int* __restrict__ cnt, int* __restrict__ fill, int n) {
    int i = blockIdx.x * 256 + threadIdx.x;
    if (i < n) { cnt[i] = 1; fill[i] = 0; }   // 1 = self-loop
}

__global__ void k_count(const int* __restrict__ dst, int* __restrict__ cnt, int E) {
    int e = blockIdx.x * 256 + threadIdx.x;
    if (e < E) atomicAdd(&cnt[dst[e]], 1);
}

__global__ void k_scan1(const int* __restrict__ cnt, int* __restrict__ row_start,
                        int* __restrict__ partial, float* __restrict__ dinv, int n) {
    __shared__ int sdata[256];
    int base = blockIdx.x * 1024;
    int t = threadIdx.x;
    int v[4]; int sum = 0;
#pragma unroll
    for (int j = 0; j < 4; ++j) {
        int idx = base + t * 4 + j;
        v[j] = (idx < n) ? cnt[idx] : 0;
        if (idx < n) dinv[idx] = rsqrtf((float)v[j]);
        sum += v[j];
    }
    sdata[t] = sum;
    __syncthreads();
    for (int off = 1; off < 256; off <<= 1) {
        int x = (t >= off) ? sdata[t - off] : 0;
        __syncthreads();
        sdata[t] += x;
        __syncthreads();
    }
    int excl = sdata[t] - sum;
#pragma unroll
    for (int j = 0; j < 4; ++j) {
        int idx = base + t * 4 + j;
        if (idx < n) row_start[idx] = excl;
        excl += v[j];
    }
    if (t == 255) partial[blockIdx.x] = sdata[255];
}

__global__ void k_scan2(int* __restrict__ partial, int nb) {
    __shared__ int s[128];
    int t = threadIdx.x;
    int v = (t < nb) ? partial[t] : 0;
    s[t] = v;
    __syncthreads();
    for (int off = 1; off < 128; off <<= 1) {
        int x = (t >= off) ? s[t - off] : 0;
        __syncthreads();
        s[t] += x;
        __syncthreads();
    }
    if (t < nb) partial[t] = s[t] - v;
}

__global__ void k_scan3(int* __restrict__ row_start, const int* __restrict__ partial,
                        int n, int total) {
    int i = blockIdx.x * 256 + threadIdx.x;
    if (i < n) row_start[i] += partial[i >> 10];
    if (i == 0) row_start[n] = total;
}

__global__ void k_fill(const int* __restrict__ src, const int* __restrict__ dst,
                       const int* __restrict__ row_start, int* __restrict__ fill,
                       int* __restrict__ csr_src, int E, int n) {
    int i = blockIdx.x * 256 + threadIdx.x;
    int total = E + n;
    if (i >= total) return;
    int s, d;
    if (i < E) { s = src[i]; d = dst[i]; }
    else       { s = d = i - E; }
    int pos = row_start[d] + atomicAdd(&fill[d], 1);
    csr_src[pos] = s;
}

// ---------------- weight convert / decompose ----------------

// fp16 single (layer 1):
__global__ void k_wcvt16(const float* __restrict__ W, int N, int K,
                         unsigned short* __restrict__ Wh, int NPAD, int KPAD) {
    int i = blockIdx.x * 256 + threadIdx.x;
    if (i >= NPAD * KPAD) return;
    int r = i / KPAD, k = i - r * KPAD;
    float x = (r < N && k < K) ? W[r * K + k] : 0.f;
    Wh[i] = __builtin_bit_cast(unsigned short, (_Float16)x);
}
// fp16 pair, lo pre-scaled x2048 (layers 2/3):
__global__ void k_wdec16(const float* __restrict__ W, int N, int K,
                         unsigned short* __restrict__ Wh, unsigned short* __restrict__ Wl,
                         int NPAD, int KPAD) {
    int i = blockIdx.x * 256 + threadIdx.x;
    if (i >= NPAD * KPAD) return;
    int r = i / KPAD, k = i - r * KPAD;
    float x = (r < N && k < K) ? W[r * K + k] : 0.f;
    _Float16 h = (_Float16)x;
    _Float16 l = (_Float16)((x - (float)h) * 2048.0f);
    Wh[i] = __builtin_bit_cast(unsigned short, h);
    Wl[i] = __builtin_bit_cast(unsigned short, l);
}

// ---------------- resident-W MFMA GEMM ----------------
// 512 thr = 8 waves x 32 rows (BM=256). Entire W block (NPAD x KP, hi [+lo])
// staged to LDS once; K-loop has NO barriers. blockIdx.y = col-block.
// MODE 0: A fp32 -> cvt fp16 in-register. MODE 1: A fp16 direct.

struct A8 { f32x4 lo, hi; };

template <int NFC, int KP, int HILO, int MODE, typename AT>
__global__ __launch_bounds__(512, 2)
void gemm_res(const AT* __restrict__ A, int lda, int M, int K,
              const unsigned short* __restrict__ Wh,
              const unsigned short* __restrict__ Wl,
              const float* __restrict__ dinv,
              _Float16* __restrict__ H16, int ldh, int Nout) {
    constexpr int NPAD = NFC * 16;         // cols in this block
    constexpr int CHH  = NPAD * KP / 8;    // 16-B chunks per half
    constexpr int CHT  = CHH * (1 + HILO);
    constexpr int NIT  = (CHT + 511) / 512;
    constexpr int SB   = NPAD * 64;        // LDS bytes per K-step block
    constexpr int HB   = CHH * 16;         // byte offset of lo half
    constexpr int NS   = KP / 32;
    __shared__ char lds[CHT * 16];

    const int tid  = threadIdx.x;
    const int wv   = tid >> 6;
    const int lane = tid & 63;
    const int lr   = lane & 15;
    const int kq   = lane >> 4;
    const int m0   = blockIdx.x * 256;
    const int col0 = blockIdx.y * NPAD;

    const unsigned short* WhB = Wh + (size_t)col0 * KP;
    const unsigned short* WlB = Wl + (size_t)col0 * KP;

    // ---- stage entire W block (linear LDS dest = c*16, swizzled source) ----
#pragma unroll
    for (int i = 0; i < NIT; ++i) {
        int c = tid + i * 512;
        if ((CHT % 512 == 0) || (c < CHT)) {
            int h  = (HILO && c >= CHH) ? 1 : 0;
            int cc = c - h * CHH;
            int s  = cc / (NPAD * 4);
            int rm = cc - s * (NPAD * 4);
            int r  = rm >> 2;
            int sl = rm & 3;
            int gs = sl ^ (r & 3);         // involutory slot swizzle (source side)
            const unsigned short* gp = (h ? WlB : WhB) + (size_t)r * KP + s * 32 + gs * 8;
            gload_lds16(gp, lds + (size_t)c * 16);
        }
    }

    int arow0 = m0 + wv * 32 + lr;       if (arow0 >= M) arow0 = M - 1;
    int arow1 = m0 + wv * 32 + 16 + lr;  if (arow1 >= M) arow1 = M - 1;
    const AT* Arow0 = A + (size_t)arow0 * lda;
    const AT* Arow1 = A + (size_t)arow1 * lda;

    auto loadA32 = [&](const AT* Arow, int s) -> A8 {
        A8 o;
        int kb = s * 32 + kq * 8;
        if (kb + 8 <= K) {
            const float* ap = (const float*)Arow + kb;
            o.lo = *(const f32x4*)ap;
            o.hi = *(const f32x4*)(ap + 4);
        } else {
#pragma unroll
            for (int i = 0; i < 4; ++i) {
                int k0 = kb + i, k1 = kb + 4 + i;
                o.lo[i] = (k0 < K) ? (float)Arow[k0] : 0.f;
                o.hi[i] = (k1 < K) ? (float)Arow[k1] : 0.f;
            }
        }
        return o;
    };
    auto loadA16 = [&](const AT* Arow, int s) -> short8 {
        int kb = s * 32 + kq * 8;
        if (kb + 8 <= K) return *(const short8*)((const unsigned short*)Arow + kb);
        short8 o;
        const unsigned short* ap = (const unsigned short*)Arow;
#pragma unroll
        for (int i = 0; i < 8; ++i) o[i] = (kb + i < K) ? (short)ap[kb + i] : (short)0;
        return o;
    };
    auto cvtA = [&](const A8& a) -> f16x8 {
        f16x8 o;
#pragma unroll
        for (int i = 0; i < 4; ++i) {
            o[i]     = (_Float16)a.lo[i];
            o[4 + i] = (_Float16)a.hi[i];
        }
        return o;
    };

    f32x4 acP[NFC], acQ[NFC], alP[NFC], alQ[NFC];
#pragma unroll
    for (int f = 0; f < NFC; ++f) {
        acP[f] = (f32x4){0.f, 0.f, 0.f, 0.f};
        acQ[f] = (f32x4){0.f, 0.f, 0.f, 0.f};
        alP[f] = (f32x4){0.f, 0.f, 0.f, 0.f};
        alQ[f] = (f32x4){0.f, 0.f, 0.f, 0.f};
    }

    __syncthreads();                       // W resident; no barriers after this

    const int ro = lr * 64 + ((kq ^ (lr & 3)) << 4);   // swizzled read offset

#pragma unroll
    for (int s = 0; s < NS; ++s) {
        f16x8 a0, a1;
        if constexpr (MODE == 0) {
            a0 = cvtA(loadA32(Arow0, s));
            a1 = cvtA(loadA32(Arow1, s));
        } else {
            a0 = __builtin_bit_cast(f16x8, loadA16(Arow0, s));
            a1 = __builtin_bit_cast(f16x8, loadA16(Arow1, s));
        }
        const char* bb = lds + s * SB;
#pragma unroll
        for (int f = 0; f < NFC; ++f) {
            f16x8 bh = __builtin_bit_cast(f16x8, *(const short8*)(bb + f * 1024 + ro));
            acP[f] = __builtin_amdgcn_mfma_f32_16x16x32_f16(a0, bh, acP[f], 0, 0, 0);
            acQ[f] = __builtin_amdgcn_mfma_f32_16x16x32_f16(a1, bh, acQ[f], 0, 0, 0);
            if constexpr (HILO) {
                f16x8 bl = __builtin_bit_cast(f16x8, *(const short8*)(bb + HB + f * 1024 + ro));
                alP[f] = __builtin_amdgcn_mfma_f32_16x16x32_f16(a0, bl, alP[f], 0, 0, 0);
                alQ[f] = __builtin_amdgcn_mfma_f32_16x16x32_f16(a1, bl, alQ[f], 0, 0, 0);
            }
        }
    }

    // ---- store: D row=(lane>>4)*4+j, col=lane&15; scale dinv, cast fp16 ----
    {
        const int rbase = m0 + wv * 32 + kq * 4;
        float dv[4];
#pragma unroll
        for (int j = 0; j < 4; ++j) {
            int row = rbase + j;
            dv[j] = (row < M) ? dinv[row] : 0.f;
        }
#pragma unroll
        for (int f = 0; f < NFC; ++f) {
            int col = col0 + f * 16 + lr;
            if (col >= Nout) continue;
#pragma unroll
            for (int j = 0; j < 4; ++j) {
                int row = rbase + j;
                if (row >= M) continue;
                float v = acP[f][j];
                if constexpr (HILO) v += alP[f][j] * (1.0f / 2048.0f);
                H16[(size_t)row * ldh + col] = (_Float16)(v * dv[j]);
            }
        }
    }
    {
        const int rbase = m0 + wv * 32 + 16 + kq * 4;
        float dv[4];
#pragma unroll
        for (int j = 0; j < 4; ++j) {
            int row = rbase + j;
            dv[j] = (row < M) ? dinv[row] : 0.f;
        }
#pragma unroll
        for (int f = 0; f < NFC; ++f) {
            int col = col0 + f * 16 + lr;
            if (col >= Nout) continue;
#pragma unroll
            for (int j = 0; j < 4; ++j) {
                int row = rbase + j;
                if (row >= M) continue;
                float v = acQ[f][j];
                if constexpr (HILO) v += alQ[f][j] * (1.0f / 2048.0f);
                H16[(size_t)row * ldh + col] = (_Float16)(v * dv[j]);
            }
        }
    }
}

// ---------------- aggregation: out = dinv[d] * sum_e h16[src_e] + b -----------------

template <int F, bool RELU>
__global__ __launch_bounds__(256)
void agg_f16(const _Float16* __restrict__ h, const int* __restrict__ row_start,
             const int* __restrict__ csr_src, const float* __restrict__ dinv,
             const float* __restrict__ bias, _Float16* __restrict__ out, int n,
             int ldo) {
    constexpr int LPN = F / 4;
    constexpr int NPW = 64 / LPN;
    int wave = blockIdx.x * 4 + (threadIdx.x >> 6);
    int lane = threadIdx.x & 63;
    int sub  = lane / LPN;
    int fi   = lane - sub * LPN;
    int node = wave * NPW + sub;
    if (sub >= NPW || node >= n) return;
    int f = fi * 4;
    const _Float16* hf = h + f;

    f32x4 acc = {0.f, 0.f, 0.f, 0.f};
    int e0 = row_start[node], e1 = row_start[node + 1];
    int e = e0;
    for (; e + 4 <= e1; e += 4) {
        int s0 = csr_src[e + 0];
        int s1 = csr_src[e + 1];
        int s2 = csr_src[e + 2];
        int s3 = csr_src[e + 3];
        f16x4 v0 = *(const f16x4*)&hf[(size_t)s0 * F];
        f16x4 v1 = *(const f16x4*)&hf[(size_t)s1 * F];
        f16x4 v2 = *(const f16x4*)&hf[(size_t)s2 * F];
        f16x4 v3 = *(const f16x4*)&hf[(size_t)s3 * F];
        acc += __builtin_convertvector(v0, f32x4);
        acc += __builtin_convertvector(v1, f32x4);
        acc += __builtin_convertvector(v2, f32x4);
        acc += __builtin_convertvector(v3, f32x4);
    }
    for (; e < e1; ++e) {
        int s = csr_src[e];
        f16x4 v = *(const f16x4*)&hf[(size_t)s * F];
        acc += __builtin_convertvector(v, f32x4);
    }
    float dn = dinv[node];
    f32x4 b4 = *(const f32x4*)&bias[f];
    acc = acc * dn + b4;
    if (RELU) {
#pragma unroll
        for (int j = 0; j < 4; ++j) acc[j] = fmaxf(acc[j], 0.f);
    }
    f16x4 o;
#pragma unroll
    for (int j = 0; j < 4; ++j) o[j] = (_Float16)acc[j];
    *(f16x4*)&out[(size_t)node * ldo + f] = o;
}

// ---------------- tiny layer-4 helpers ----------------

__global__ void gemm_small(const _Float16* __restrict__ A, const float* __restrict__ B,
                           const float* __restrict__ dinv, float* __restrict__ C,
                           int M, int K) {
    int m = blockIdx.x * 256 + threadIdx.x;
    if (m >= M) return;
    float a0 = 0.f, a1 = 0.f, a2 = 0.f;
    for (int k = 0; k < K; ++k) {
        float a = (float)A[(size_t)m * K + k];
        a0 += a * B[0 * K + k];
        a1 += a * B[1 * K + k];
        a2 += a * B[2 * K + k];
    }
    float dv = dinv[m];
    C[(size_t)m * 3 + 0] = a0 * dv;
    C[(size_t)m * 3 + 1] = a1 * dv;
    C[(size_t)m * 3 + 2] = a2 * dv;
}

__global__ void agg_f3(const float* __restrict__ h, const int* __restrict__ row_start,
                       const int* __restrict__ csr_src, const float* __restrict__ dinv,
                       const float* __restrict__ bias, float* __restrict__ out, int n) {
    int i = blockIdx.x * 256 + threadIdx.x;
    if (i >= n * 3) return;
    int node = i / 3;
    int f = i - node * 3;
    float acc = 0.f;
    int e1 = row_start[node + 1];
    for (int e = row_start[node]; e < e1; ++e) {
        int s = csr_src[e];
        acc += h[(size_t)s * 3 + f];
    }
    out[i] = acc * dinv[node] + bias[f];
}

// ---------------------------------------------------------------------------

extern "C" void kernel_launch(void* const* d_in, const int* in_sizes, int n_in,
                              void* d_out, int out_size, void* d_ws, size_t ws_size,
                              hipStream_t stream) {
    const float* x   = (const float*)d_in[0];
    const int*   ei  = (const int*)d_in[1];
    const float* W1  = (const float*)d_in[2];
    const float* b1  = (const float*)d_in[3];
    const float* W1b = (const float*)d_in[4];
    const float* b1b = (const float*)d_in[5];
    const float* W2b = (const float*)d_in[6];
    const float* b2b = (const float*)d_in[7];
    const float* W2  = (const float*)d_in[8];
    const float* b2  = (const float*)d_in[9];
    float* out = (float*)d_out;

    const int F_IN = 500, H1 = 200, H2 = 100, H3 = 40;
    const int N = in_sizes[0] / F_IN;
    const int E = in_sizes[1] / 2;
    const int* src = ei;
    const int* dst = ei + E;

    size_t off = 0;
    auto alloc = [&](size_t bytes) -> void* {
        void* p = (char*)d_ws + off;
        off += (bytes + 255) & ~(size_t)255;
        return p;
    };
    int*   cnt       = (int*)  alloc((size_t)N * 4);
    int*   row_start = (int*)  alloc((size_t)(N + 1) * 4);
    int*   fill      = (int*)  alloc((size_t)N * 4);
    int*   partial   = (int*)  alloc(128 * 4);
    float* dinv      = (float*)alloc((size_t)N * 4);
    int*   csr_src   = (int*)  alloc((size_t)(E + N) * 4);
    unsigned short* wh1 = (unsigned short*)alloc(224 * 512 * 2);
    unsigned short* wh2 = (unsigned short*)alloc(112 * 224 * 2);
    unsigned short* wl2 = (unsigned short*)alloc(112 * 224 * 2);
    unsigned short* wh3 = (unsigned short*)alloc(48 * 128 * 2);
    unsigned short* wl3 = (unsigned short*)alloc(48 * 128 * 2);
    _Float16* h16   = (_Float16*)alloc((size_t)N * H1 * 2);  // gemm outputs (scaled fp16)
    _Float16* act16 = (_Float16*)alloc((size_t)N * H1 * 2);  // agg outputs (fp16)
    float*    bufC  = (float*)   alloc((size_t)N * 3 * 4);   // layer-4 gemm out

    int gN  = (N + 255) / 256;
    int gE  = (E + 255) / 256;
    int gEN = (E + N + 255) / 256;
    int nb  = (N + 1023) / 1024;

    // --- CSR build ---
    k_init <<<gN, 256, 0, stream>>>(cnt, fill, N);
    k_count<<<gE, 256, 0, stream>>>(dst, cnt, E);
    k_scan1<<<nb, 256, 0, stream>>>(cnt, row_start, partial, dinv, N);
    k_scan2<<<1, 128, 0, stream>>>(partial, nb);
    k_scan3<<<gN, 256, 0, stream>>>(row_start, partial, N, E + N);
    k_fill <<<gEN, 256, 0, stream>>>(src, dst, row_start, fill, csr_src, E, N);

    // --- weight convert / decompose ---
    k_wcvt16<<<(224 * 512 + 255) / 256, 256, 0, stream>>>(W1,  H1, F_IN, wh1, 224, 512);
    k_wdec16<<<(112 * 224 + 255) / 256, 256, 0, stream>>>(W1b, H2, H1, wh2, wl2, 112, 224);
    k_wdec16<<<( 48 * 128 + 255) / 256, 256, 0, stream>>>(W2b, H3, H2, wh3, wl3,  48, 128);

    const int gM = (N + 255) / 256;   // BM = 256

    // --- layer 1: 2 col-halves of 112, fp16-single W, no-barrier K-loop ---
    gemm_res<7, 512, 0, 0, float><<<dim3(gM, 2), 512, 0, stream>>>(
        x, F_IN, N, F_IN, wh1, wh1, dinv, h16, H1, H1);
    agg_f16<200, true><<<(N + 3) / 4, 256, 0, stream>>>(h16, row_start, csr_src, dinv,
                                                        b1, act16, N, 200);
    // --- layer 2: full resident W hi/lo ---
    gemm_res<7, 224, 1, 1, _Float16><<<dim3(gM, 1), 512, 0, stream>>>(
        act16, 200, N, H1, wh2, wl2, dinv, h16, H2, H2);
    agg_f16<100, true><<<(N / 2 + 3) / 4, 256, 0, stream>>>(h16, row_start, csr_src, dinv,
                                                            b1b, act16, N, 112);
    // --- layer 3: full resident W hi/lo (A stride 112) ---
    gemm_res<3, 128, 1, 1, _Float16><<<dim3(gM, 1), 512, 0, stream>>>(
        act16, 112, N, H2, wh3, wl3, dinv, h16, H3, H3);
    {
        int waves = (N + 5) / 6, blocks = (waves + 3) / 4;
        agg_f16<40, true><<<blocks, 256, 0, stream>>>(h16, row_start, csr_src, dinv,
                                                      b2b, act16, N, 40);
    }
    // --- layer 4 ---
    gemm_small<<<(N + 255) / 256, 256, 0, stream>>>(act16, W2, dinv, bufC, N, H3);
    agg_f3<<<(N * 3 + 255) / 256, 256, 0, stream>>>(bufC, row_start, csr_src, dinv,
                                                    b2, out, N);
}